// Round 18
// baseline (63.178 us; speedup 1.0000x reference)
//
#include <hip/hip_runtime.h>
#include <stdint.h>
#include <math.h>

#define NB 4
#define NH 16
#define NS 1024
#define ND 64
#define QT 64            // q rows per block (4 row-groups x 16; two wave-halves share them)
#define KT 64            // k cols per tile
#define KSL 512          // k-slice per wave-half
#define NKT (KSL/KT)     // 8 tiles per half
#define LDH 72           // f16 row pad
#define SQRT_SCALE 120.11224f             // sqrt(10000*log2(e)); folded into Q and K
#define SCALE_LOG2E 14426.950408889634f   // 10000*log2(e) (exact-recompute scale)
#define MARGIN 512.0f    // candidacy window (log2 units)
#define CAND_C 4         // per-lane candidate slots
#define P_RNG_MIN 7.4505806e-9f           // 2^-27: below this dropout is irrelevant

typedef _Float16 half8 __attribute__((ext_vector_type(8)));
typedef _Float16 half4 __attribute__((ext_vector_type(4)));
typedef float    f32x4 __attribute__((ext_vector_type(4)));

// XOR-swizzled half-index for a [rows][LDH] f16 LDS array (T2; involution both sides).
__device__ __forceinline__ int swz(int row, int col){
  return row*LDH + ((((col>>3) ^ ((row>>2)&7)))<<3) + (col&7);
}

// ---------------- threefry2x32, key = (0, 42) ----------------
__device__ __forceinline__ void threefry2x32(uint32_t x0, uint32_t x1,
                                             uint32_t &o0, uint32_t &o1){
  const uint32_t ks0 = 0u, ks1 = 42u, ks2 = 0x1BD11BF0u; // 0x1BD11BDA ^ 0 ^ 42
  x0 += ks0; x1 += ks1;
#define TFR(r) { x0 += x1; x1 = __builtin_rotateleft32(x1,(r)); x1 ^= x0; }
  TFR(13) TFR(15) TFR(26) TFR(6)
  x0 += ks1; x1 += ks2 + 1u;
  TFR(17) TFR(29) TFR(16) TFR(24)
  x0 += ks2; x1 += ks0 + 2u;
  TFR(13) TFR(15) TFR(26) TFR(6)
  x0 += ks0; x1 += ks1 + 3u;
  TFR(17) TFR(29) TFR(16) TFR(24)
  x0 += ks1; x1 += ks2 + 4u;
  TFR(13) TFR(15) TFR(26) TFR(6)
  x0 += ks2; x1 += ks0 + 5u;
#undef TFR
  o0 = x0; o1 = x1;
}

// JAX partitionable threefry: bits(i) = o0^o1 of threefry(key, (0, i));
// keep iff (bits>>9) < 0x733333  (uniform < 0.9). Validated rounds 2..17.
__device__ __forceinline__ uint32_t keep_flat(uint32_t flat){
  uint32_t o0, o1;
  threefry2x32(0u, flat, o0, o1);
  return ((o0 ^ o1) >> 9) < 0x733333u ? 1u : 0u;
}

// Argmax-window flash attention with IN-BLOCK K-SPLIT: waves 0-3 scan K[0,512),
// waves 4-7 scan K[512,1024) for the same 64 q-rows -> 8192 waves (32/CU, HW max),
// half the sequential tiles per wave. Slice-local gating is lossless
// (m_slice <= m_global => slice gate is looser). Merge across the two halves
// happens in the epilogue via LDS (candidates were already there).
__global__ __launch_bounds__(512, 8) void attn_ksplit(
    const float* __restrict__ Qg, const float* __restrict__ Kg,
    const float* __restrict__ Vg, float* __restrict__ Og)
{
  __shared__ _Float16 KL[KT*LDH];           // K tile, lo half (kc 0..63 of slice 0)
  __shared__ _Float16 KH[KT*LDH];           // K tile, hi half (slice 1)
  __shared__ float    candS[512*CAND_C];    // per-thread candidate scores -> p
  __shared__ uint32_t candK[512*CAND_C];    // per-thread candidate k indices
  __shared__ float    mredS[512];           // per-thread smax (epilogue reduce)
  __shared__ float    lredS[512];           // per-thread l partial

  const int tid  = threadIdx.x;
  const int wid  = tid >> 6;      // 0..7
  const int half = wid >> 2;      // 0: K[0,512)  1: K[512,1024)
  const int wg   = wid & 3;       // row-group 0..3 (16 rows each)
  const int lane = tid & 63;
  const int lhi  = lane >> 4;     // 0..3
  const int llo  = lane & 15;
  const int cbase = tid * CAND_C;

  #pragma unroll
  for (int r = 0; r < CAND_C; ++r) { candS[cbase+r] = 0.f; candK[cbase+r] = 0u; }
  int nc = 0;

  // bijective XCD swizzle: 1024 blocks, 8 XCDs, 128 contiguous work items each
  const int swzb = (blockIdx.x & 7) * 128 + (blockIdx.x >> 3);
  const int bh  = swzb >> 4;      // 0..63
  const int qt  = swzb & 15;      // 0..15 (64-row q tiles)

  const uint32_t qrow_flat = (uint32_t)(bh*NS + qt*QT + wg*16 + llo);

  // ---- Q fp16 B-fragments (scaled); 1-product approx scan
  half8 qh[2];
  {
    const float* qsrc = Qg + (size_t)qrow_flat*ND;
    #pragma unroll
    for (int ks = 0; ks < 2; ++ks) {
      const float* p = qsrc + ks*32 + lhi*8;
      float4 a = *(const float4*)p;
      float4 b = *(const float4*)(p + 4);
      float v[8] = {a.x,a.y,a.z,a.w,b.x,b.y,b.z,b.w};
      #pragma unroll
      for (int j = 0; j < 8; ++j) qh[ks][j] = (_Float16)(v[j] * SQRT_SCALE);
    }
  }

  const float* srcK = Kg + (size_t)bh*NS*ND;
  const float* srcV = Vg + (size_t)bh*NS*ND;
  const int frow = tid >> 4;          // 0..31
  const int fcol = (tid & 15) * 4;    // d offset

  // per iter stage 2x64 rows: KL rows kt*64+r, KH rows 512+kt*64+r
  float4 pk[4];
  auto gload = [&](int kt){
    #pragma unroll
    for (int h = 0; h < 2; ++h)
      #pragma unroll
      for (int r = 0; r < 2; ++r)
        pk[h*2+r] = *(const float4*)(srcK +
            (size_t)(h*KSL + kt*KT + frow + 32*r)*ND + fcol);
  };
  auto stage = [&](){
    #pragma unroll
    for (int h = 0; h < 2; ++h) {
      _Float16* dst = h ? KH : KL;
      #pragma unroll
      for (int r = 0; r < 2; ++r) {
        const int row = frow + 32*r;
        float4 v = pk[h*2+r];
        half4 h4;
        h4[0] = (_Float16)(v.x * SQRT_SCALE);
        h4[1] = (_Float16)(v.y * SQRT_SCALE);
        h4[2] = (_Float16)(v.z * SQRT_SCALE);
        h4[3] = (_Float16)(v.w * SQRT_SCALE);
        *(half4*)&dst[swz(row, fcol)] = h4;
      }
    }
  };

  gload(0);

  float m_run = -INFINITY;

  for (int kt = 0; kt < NKT; ++kt) {
    __syncthreads();   // A: prior tile's LDS reads complete
    stage();
    __syncthreads();   // B: tiles ready
    if (kt + 1 < NKT) gload(kt + 1);

    const _Float16* KB = half ? KH : KL;

    // ---- approx QK^T: S^T[k][q] (C: row=k=nt*16+4lhi+reg, col=q=llo)
    f32x4 St[4];
    #pragma unroll
    for (int nt=0;nt<4;++nt){ St[nt][0]=0.f;St[nt][1]=0.f;St[nt][2]=0.f;St[nt][3]=0.f; }
    #pragma unroll
    for (int ks = 0; ks < 2; ++ks) {
      #pragma unroll
      for (int nt = 0; nt < 4; ++nt) {
        half8 kh = *(const half8*)&KB[swz(nt*16 + llo, ks*32 + lhi*8)];
        St[nt] = __builtin_amdgcn_mfma_f32_16x16x32_f16(kh, qh[ks], St[nt], 0, 0, 0);
      }
    }

    // ---- running max + candidate scan (slice-local; lossless gating)
    float tm = -INFINITY;
    #pragma unroll
    for (int nt = 0; nt < 4; ++nt) {
      float a = fmaxf(fmaxf(St[nt][0], St[nt][1]), fmaxf(St[nt][2], St[nt][3]));
      tm = fmaxf(tm, a);
    }
    float rm = tm;
    rm = fmaxf(rm, __shfl_xor(rm, 16));
    rm = fmaxf(rm, __shfl_xor(rm, 32));
    const float mnew = fmaxf(m_run, rm);
    const float gate = mnew - MARGIN;
    if (tm > gate) {
      #pragma unroll
      for (int i = 0; i < 16; ++i) {
        float s = St[i>>2][i&3];
        if (s > gate) {
          uint32_t k = (uint32_t)(half*KSL + kt*KT + ((i>>2)<<4) + 4*lhi + (i&3));
          if (nc == CAND_C) {             // compact stale entries
            int w = 0;
            #pragma unroll
            for (int r = 0; r < CAND_C; ++r) {
              float sr = candS[cbase+r]; uint32_t kr = candK[cbase+r];
              if (sr > gate) { candS[cbase+w] = sr; candK[cbase+w] = kr; ++w; }
            }
            nc = w;
          }
          if (nc < CAND_C) {
            candS[cbase+nc] = s; candK[cbase+nc] = k; ++nc;
          } else {                        // statistically ~never: replace min
            int mi = 0; float ms = candS[cbase];
            #pragma unroll
            for (int r = 1; r < CAND_C; ++r) {
              float sr = candS[cbase+r];
              if (sr < ms) { ms = sr; mi = r; }
            }
            if (s > ms) { candS[cbase+mi] = s; candK[cbase+mi] = k; }
          }
        }
      }
    }
    m_run = mnew;
  }

  // ---------------- epilogue (two-slice merge in LDS) ----------------
  const float gateF = m_run - MARGIN;   // slice-local gate (lossless)
  const float* qrow = Qg + (size_t)qrow_flat*ND;

  // exact f32 rescore of surviving candidates (own slots)
  float smax_own = -INFINITY;
  #pragma unroll
  for (int r = 0; r < CAND_C; ++r) {
    float se = -INFINITY;
    if (r < nc && candS[cbase+r] > gateF) {
      const float* kp = srcK + (size_t)candK[cbase+r]*ND;
      float acc = 0.f;
      #pragma unroll
      for (int d = 0; d < ND; d += 4) {
        float4 qv = *(const float4*)(qrow + d);
        float4 kv = *(const float4*)(kp + d);
        acc = fmaf(qv.x, kv.x, acc); acc = fmaf(qv.y, kv.y, acc);
        acc = fmaf(qv.z, kv.z, acc); acc = fmaf(qv.w, kv.w, acc);
      }
      se = acc * SCALE_LOG2E;
    }
    candS[cbase+r] = se;                 // -inf for dead slots
    smax_own = fmaxf(smax_own, se);
  }
  mredS[tid] = smax_own;
  __syncthreads();

  // row max over the row's 8 owner lanes (2 wave-halves x 4 lhi)
  float mstar = -INFINITY;
  #pragma unroll
  for (int l2 = 0; l2 < 8; ++l2) {
    const int ptid = ((l2 >> 2) << 8) + (wg << 6) + ((l2 & 3) << 4) + llo;
    mstar = fmaxf(mstar, mredS[ptid]);
  }

  // softmax numerators + l partial + exact dropout (own slots)
  float lown = 0.f;
  #pragma unroll
  for (int r = 0; r < CAND_C; ++r) {
    float se = candS[cbase+r];
    float p = exp2f(se - mstar);         // 0 for dead (-inf)
    lown += p;                           // l is PRE-dropout (matches ref)
    if (p > P_RNG_MIN) {
      if (!keep_flat(qrow_flat*NS + candK[cbase+r])) p = 0.f;
    }
    candS[cbase+r] = p;
  }
  lredS[tid] = lown;
  __syncthreads();

  float lsum = 0.f;
  #pragma unroll
  for (int l2 = 0; l2 < 8; ++l2) {
    const int ptid = ((l2 >> 2) << 8) + (wg << 6) + ((l2 & 3) << 4) + llo;
    lsum += lredS[ptid];
  }

  // gather: lane covers d = half*32 + lhi*8 .. +8; iterate the row's 32 slots
  float o[8];
  #pragma unroll
  for (int j = 0; j < 8; ++j) o[j] = 0.f;
  const int d0 = half*32 + lhi*8;
  #pragma unroll
  for (int l2 = 0; l2 < 8; ++l2) {
    const int ptid = ((l2 >> 2) << 8) + (wg << 6) + ((l2 & 3) << 4) + llo;
    #pragma unroll
    for (int r = 0; r < CAND_C; ++r) {
      float p = candS[ptid*CAND_C + r];
      if (p > 0.f) {
        const float* vp = srcV + (size_t)candK[ptid*CAND_C + r]*ND + d0;
        float4 v0 = *(const float4*)(vp);
        float4 v1 = *(const float4*)(vp + 4);
        o[0]=fmaf(p,v0.x,o[0]); o[1]=fmaf(p,v0.y,o[1]);
        o[2]=fmaf(p,v0.z,o[2]); o[3]=fmaf(p,v0.w,o[3]);
        o[4]=fmaf(p,v1.x,o[4]); o[5]=fmaf(p,v1.y,o[5]);
        o[6]=fmaf(p,v1.z,o[6]); o[7]=fmaf(p,v1.w,o[7]);
      }
    }
  }
  const float inv = 1.0f / (0.9f * lsum);
  float* op = Og + (size_t)qrow_flat*ND + d0;
  float4 w0 = {o[0]*inv, o[1]*inv, o[2]*inv, o[3]*inv};
  float4 w1 = {o[4]*inv, o[5]*inv, o[6]*inv, o[7]*inv};
  *(float4*)(op)     = w0;
  *(float4*)(op + 4) = w1;
}

extern "C" void kernel_launch(void* const* d_in, const int* in_sizes, int n_in,
                              void* d_out, int out_size, void* d_ws, size_t ws_size,
                              hipStream_t stream) {
  const float* x1  = (const float*)d_in[0];   // Q
  const float* kw  = (const float*)d_in[1];   // K
  const float* val = (const float*)d_in[2];   // V
  float* out = (float*)d_out;
  attn_ksplit<<<dim3(NB*NH*(NS/QT)), dim3(512), 0, stream>>>(x1, kw, val, out);
}